// Round 3
// baseline (457.905 us; speedup 1.0000x reference)
//
#include <hip/hip_runtime.h>
#include <stdint.h>

// ---------------- common helpers ----------------
typedef __attribute__((ext_vector_type(8))) short short8;
typedef __attribute__((ext_vector_type(4))) short short4v;
typedef __attribute__((ext_vector_type(4))) float float4v;
typedef __attribute__((ext_vector_type(8))) __bf16 bf16x8;

__device__ __forceinline__ float4v mfma16x16x32(short8 a, short8 b, float4v c) {
  return __builtin_amdgcn_mfma_f32_16x16x32_bf16(
      __builtin_bit_cast(bf16x8, a), __builtin_bit_cast(bf16x8, b), c, 0, 0, 0);
}

// float -> bf16 (RNE), as raw short
__device__ __forceinline__ short f2bf(float f) {
  uint32_t u = __builtin_bit_cast(uint32_t, f);
  u += 0x7fffu + ((u >> 16) & 1u);
  return (short)(u >> 16);
}

__device__ __forceinline__ float bf2f(short s) {
  return __builtin_bit_cast(float, ((uint32_t)(uint16_t)s) << 16);
}

// ---------------- fp32 -> bf16 elementwise (n multiple of 4) ----------------
__global__ __launch_bounds__(256) void convert_f2b(
    const float* __restrict__ src, short* __restrict__ dst, int n4) {
  int i = blockIdx.x * blockDim.x + threadIdx.x;
  const int stride = gridDim.x * blockDim.x;
  for (; i < n4; i += stride) {
    float4v v = *(const float4v*)(src + (long)i * 4);
    short4v o;
#pragma unroll
    for (int r = 0; r < 4; r++) o[r] = f2bf(v[r]);
    *(short4v*)(dst + (long)i * 4) = o;
  }
}

// ---------------- NT GEMM: C[m,n] = scale * sum_k A[m,k]*B[n,k] ----------------
// A:[M][K] bf16 K-contig, B:[N][K] bf16 K-contig. 128x128 tile, BK=32,
// 4 waves in 2x2, each wave 64x64 (4x4 MFMA tiles). grid=(N/128, M/128, batch).
// TRANS_STORE=1: C bf16 at [n*ldc+m]; OUT_F32=1: C fp32 at [m*ldc+n];
// else bf16 at [m*ldc+n].
template <int TRANS_STORE, int OUT_F32>
__global__ __launch_bounds__(256) void gemm_nt(
    const short* __restrict__ A, long sA,
    const short* __restrict__ B, long sB,
    void* __restrict__ C, long sC,
    int K, int ldc, float scale) {
  __shared__ alignas(16) short lA[128 * 32];
  __shared__ alignas(16) short lB[128 * 32];
  const int tid = threadIdx.x;
  const int lane = tid & 63, w = tid >> 6;
  const int quad = lane >> 4, l16 = lane & 15;
  const int wm = w >> 1, wn = w & 1;
  const long m0 = (long)blockIdx.y * 128, n0 = (long)blockIdx.x * 128;
  A += blockIdx.z * sA;
  B += blockIdx.z * sB;

  float4v acc[4][4];
#pragma unroll
  for (int i = 0; i < 4; i++)
#pragma unroll
    for (int j = 0; j < 4; j++) acc[i][j] = (float4v)0.0f;

  const int srow = tid >> 2;       // 0..63
  const int scol = (tid & 3) * 8;  // element offset in BK

  for (int kt = 0; kt < K; kt += 32) {
    short8 a0 = *(const short8*)&A[(m0 + srow) * K + kt + scol];
    short8 a1 = *(const short8*)&A[(m0 + 64 + srow) * K + kt + scol];
    short8 b0 = *(const short8*)&B[(n0 + srow) * K + kt + scol];
    short8 b1 = *(const short8*)&B[(n0 + 64 + srow) * K + kt + scol];
    *(short8*)&lA[tid * 8] = a0;  // lA row-major [128][32]
    *(short8*)&lA[2048 + tid * 8] = a1;
    *(short8*)&lB[tid * 8] = b0;
    *(short8*)&lB[2048 + tid * 8] = b1;
    __syncthreads();

    short8 af[4], bf[4];
#pragma unroll
    for (int t = 0; t < 4; t++) {
      af[t] = *(const short8*)&lA[(wm * 64 + t * 16 + l16) * 32 + quad * 8];
      bf[t] = *(const short8*)&lB[(wn * 64 + t * 16 + l16) * 32 + quad * 8];
    }
#pragma unroll
    for (int i = 0; i < 4; i++)
#pragma unroll
      for (int j = 0; j < 4; j++)
        acc[i][j] = mfma16x16x32(af[i], bf[j], acc[i][j]);
    __syncthreads();
  }

  // C/D layout: col = lane&15 (n), row = quad*4 + reg (m)
  const int cm = wm * 64 + quad * 4;
  const int cn = wn * 64 + l16;
  if (OUT_F32) {
    float* Cf = (float*)C + blockIdx.z * sC;
#pragma unroll
    for (int i = 0; i < 4; i++)
#pragma unroll
      for (int j = 0; j < 4; j++) {
        const long gn = n0 + cn + j * 16;
#pragma unroll
        for (int r = 0; r < 4; r++)
          Cf[(m0 + cm + i * 16 + r) * (long)ldc + gn] = acc[i][j][r] * scale;
      }
  } else if (TRANS_STORE) {
    short* Cs = (short*)C + blockIdx.z * sC;
#pragma unroll
    for (int i = 0; i < 4; i++)
#pragma unroll
      for (int j = 0; j < 4; j++) {
        const long gm = m0 + cm + i * 16;
        const long gn = n0 + cn + j * 16;
        short4v pk;
#pragma unroll
        for (int r = 0; r < 4; r++) pk[r] = f2bf(acc[i][j][r] * scale);
        *(short4v*)&Cs[gn * (long)ldc + gm] = pk;  // gm multiple of 4 -> 8B aligned
      }
  } else {
    short* Cs = (short*)C + blockIdx.z * sC;
#pragma unroll
    for (int i = 0; i < 4; i++)
#pragma unroll
      for (int j = 0; j < 4; j++) {
        const long gn = n0 + cn + j * 16;
#pragma unroll
        for (int r = 0; r < 4; r++)
          Cs[(m0 + cm + i * 16 + r) * (long)ldc + gn] = f2bf(acc[i][j][r] * scale);
      }
  }
}

// ---------------- vis fp32 (b,c,s) -> visT bf16 (b,s,c) ----------------
// grid=(S/64, C/64, Bg), 256 thr, 64x64 LDS tile.
__global__ __launch_bounds__(256) void transpose_f2b(
    const float* __restrict__ vis, short* __restrict__ visT) {
  __shared__ alignas(16) short buf[64][68];  // 68 breaks conflicts, keeps 8B align
  const int tid = threadIdx.x;
  const long bz = blockIdx.z;
  const long s0 = (long)blockIdx.x * 64;
  const long c0 = (long)blockIdx.y * 64;
  const float* src = vis + bz * 512 * 4096;
  short* dst = visT + bz * 4096 * 512;
  const int tr = tid >> 4;         // 0..15
  const int tc4 = (tid & 15) * 4;  // 0..60
#pragma unroll
  for (int i = 0; i < 4; i++) {
    const int c = tr + i * 16;
    float4v val = *(const float4v*)&src[(c0 + c) * 4096 + s0 + tc4];
    buf[tc4 + 0][c] = f2bf(val[0]);
    buf[tc4 + 1][c] = f2bf(val[1]);
    buf[tc4 + 2][c] = f2bf(val[2]);
    buf[tc4 + 3][c] = f2bf(val[3]);
  }
  __syncthreads();
#pragma unroll
  for (int i = 0; i < 4; i++) {
    const int s = tr + i * 16;
    short4v val = *(const short4v*)&buf[s][tc4];
    *(short4v*)&dst[(s0 + s) * 512 + c0 + tc4] = val;
  }
}

// ---------------- attention: one block per (head, batch-in-group) ----------------
// q:[16][64][512] bf16 (scaled), k:[Bg][4096][512] (s,i), v:[Bg][512][4096] (i,s),
// tmp:[16][64][512] bf16. No-max softmax (logits ~N(0,1)); logits clamped to
// [-80,30] purely as NaN insurance (never active for sane inputs).
__global__ __launch_bounds__(256) void attn(
    const short* __restrict__ q, const short* __restrict__ kws,
    const short* __restrict__ vws, short* __restrict__ tmp, int b0) {
  const int h = blockIdx.x;
  const int bz = blockIdx.y;
  const int tid = threadIdx.x;
  const int lane = tid & 63, w = tid >> 6;
  const int quad = lane >> 4, l16 = lane & 15;

  __shared__ alignas(16) short lq[64 * 64];   // q tile  (t,d)
  __shared__ alignas(16) short lk[128 * 64];  // k chunk (s,d)
  __shared__ alignas(16) short lv[64 * 128];  // v chunk (d,s)
  __shared__ alignas(16) short lp[64 * 128];  // p chunk (t,s) C-layout -> A-layout
  __shared__ float lsum[64];

  const short* qb = q + ((long)(b0 + bz) * 64) * 512 + h * 64;
  const short* kb = kws + (long)bz * 4096 * 512 + h * 64;
  const short* vb = vws + (long)bz * 512 * 4096 + (long)h * 64 * 4096;

  if (tid < 64) lsum[tid] = 0.0f;
  {
    short8 v0 = *(const short8*)&qb[(tid >> 3) * 512 + (tid & 7) * 8];
    short8 v1 = *(const short8*)&qb[(32 + (tid >> 3)) * 512 + (tid & 7) * 8];
    *(short8*)&lq[tid * 8] = v0;
    *(short8*)&lq[2048 + tid * 8] = v1;
  }
  __syncthreads();

  short8 aq[4][2];  // A-frags of q, resident all kernel
#pragma unroll
  for (int mt = 0; mt < 4; mt++)
#pragma unroll
    for (int ks = 0; ks < 2; ks++)
      aq[mt][ks] = *(const short8*)&lq[(mt * 16 + l16) * 64 + ks * 32 + quad * 8];

  float4v osc[4];  // O accum: wave w owns d-tile w, all 4 t-tiles
#pragma unroll
  for (int mt = 0; mt < 4; mt++) osc[mt] = (float4v)0.0f;
  float lpart[4][4] = {};  // row-sum partials [mt][reg]

  for (int s0 = 0; s0 < 4096; s0 += 128) {
    short8 stg[8];
#pragma unroll
    for (int it = 0; it < 4; it++) {
      const int li = tid + it * 256;
      stg[it] = *(const short8*)&kb[(long)(s0 + (li >> 3)) * 512 + (li & 7) * 8];
    }
#pragma unroll
    for (int it = 0; it < 4; it++) {
      const int li = tid + it * 256;
      stg[4 + it] = *(const short8*)&vb[(long)(li >> 4) * 4096 + s0 + (li & 15) * 8];
    }
#pragma unroll
    for (int it = 0; it < 4; it++) *(short8*)&lk[(tid + it * 256) * 8] = stg[it];
#pragma unroll
    for (int it = 0; it < 4; it++) *(short8*)&lv[(tid + it * 256) * 8] = stg[4 + it];
    __syncthreads();

    // scores: wave w covers s-tiles {2w, 2w+1}
    float4v sc[4][2];
#pragma unroll
    for (int mt = 0; mt < 4; mt++)
#pragma unroll
      for (int jn = 0; jn < 2; jn++) sc[mt][jn] = (float4v)0.0f;
#pragma unroll
    for (int ks = 0; ks < 2; ks++) {
      short8 bk[2];
#pragma unroll
      for (int jn = 0; jn < 2; jn++)
        bk[jn] = *(const short8*)&lk[((2 * w + jn) * 16 + l16) * 64 + ks * 32 + quad * 8];
#pragma unroll
      for (int mt = 0; mt < 4; mt++)
#pragma unroll
        for (int jn = 0; jn < 2; jn++)
          sc[mt][jn] = mfma16x16x32(aq[mt][ks], bk[jn], sc[mt][jn]);
    }

    // p = exp(clamped score); accumulate row sums of the bf16-quantized p;
    // park p in LDS transposed from C-layout to A-operand layout.
#pragma unroll
    for (int mt = 0; mt < 4; mt++)
#pragma unroll
      for (int jn = 0; jn < 2; jn++)
#pragma unroll
        for (int r = 0; r < 4; r++) {
          const float scv = fminf(fmaxf(sc[mt][jn][r], -80.0f), 30.0f);
          const short sp = f2bf(__expf(scv));
          lpart[mt][r] += bf2f(sp);
          lp[(mt * 16 + quad * 4 + r) * 128 + (2 * w + jn) * 16 + l16] = sp;
        }
    __syncthreads();

    // PV: O[t, d(tile w)] += P · V
#pragma unroll
    for (int ks = 0; ks < 4; ks++) {
      const short8 bv = *(const short8*)&lv[(w * 16 + l16) * 128 + ks * 32 + quad * 8];
#pragma unroll
      for (int mt = 0; mt < 4; mt++) {
        const short8 ap = *(const short8*)&lp[(mt * 16 + l16) * 128 + ks * 32 + quad * 8];
        osc[mt] = mfma16x16x32(ap, bv, osc[mt]);
      }
    }
    __syncthreads();  // protect lk/lv/lp before next chunk's staging
  }

  // reduce row sums: 16 lanes (l16) of each quad-row hold disjoint s-columns
#pragma unroll
  for (int mt = 0; mt < 4; mt++)
#pragma unroll
    for (int r = 0; r < 4; r++) {
      float v = lpart[mt][r];
      v += __shfl_xor(v, 1);
      v += __shfl_xor(v, 2);
      v += __shfl_xor(v, 4);
      v += __shfl_xor(v, 8);
      if (l16 == 0) atomicAdd(&lsum[mt * 16 + quad * 4 + r], v);
    }
  __syncthreads();

  short* outp = tmp + ((long)(b0 + bz) * 64) * 512 + h * 64 + w * 16 + l16;
#pragma unroll
  for (int mt = 0; mt < 4; mt++)
#pragma unroll
    for (int r = 0; r < 4; r++) {
      const int trow = mt * 16 + quad * 4 + r;
      outp[(long)trow * 512] = f2bf(osc[mt][r] / lsum[trow]);
    }
}

// ---------------- launch ----------------
extern "C" void kernel_launch(void* const* d_in, const int* in_sizes, int n_in,
                              void* d_out, int out_size, void* d_ws, size_t ws_size,
                              hipStream_t stream) {
  (void)in_sizes; (void)n_in; (void)out_size;
  const float* vis = (const float*)d_in[0];   // [16][512][4096] fp32
  const float* lang = (const float*)d_in[1];  // [16][64][512]  fp32
  // d_in[2] = mask (int32), unused by the reference forward
  const float* Wq = (const float*)d_in[3];    // [512][512] fp32
  const float* Wk = (const float*)d_in[4];
  const float* Wv = (const float*)d_in[5];
  const float* Wo = (const float*)d_in[6];
  float* out = (float*)d_out;                 // [16][64][512] fp32

  char* ws = (char*)d_ws;
  const size_t MB = 1 << 20;
  short* q_ws = (short*)(ws + 0 * MB);    // 1 MB: scaled q bf16, (b,t,i)
  short* tmp_ws = (short*)(ws + 1 * MB);  // 1 MB: attn out bf16, (b,t,i)
  short* langb = (short*)(ws + 2 * MB);   // 1 MB
  short* Wqb = (short*)(ws + 3 * MB);     // 0.5 MB each
  short* Wkb = (short*)(ws + 3 * MB + 512 * 1024);
  short* Wvb = (short*)(ws + 4 * MB);
  short* Wob = (short*)(ws + 4 * MB + 512 * 1024);
  char* grp = ws + 5 * MB;

  const long batch_elems = 4096l * 512;  // 4 MB bf16 per batch per tensor
  // pick batch-group count so visT+k+v fit the workspace
  int g = 16;
  const int cands[5] = {1, 2, 4, 8, 16};
  for (int ci = 0; ci < 5; ci++) {
    const size_t need = 5 * MB + 3ull * (16 / cands[ci]) * batch_elems * 2;
    if (need <= ws_size) { g = cands[ci]; break; }
  }
  const int Bg = 16 / g;
  short* visT = (short*)grp;                    // [Bg][4096][512]
  short* k_ws = visT + (long)Bg * batch_elems;  // [Bg][4096][512] (s,i)
  short* v_ws = k_ws + (long)Bg * batch_elems;  // [Bg][512][4096] (i,s)

  // fp32 -> bf16 conversions (small tensors)
  convert_f2b<<<256, 256, 0, stream>>>(lang, langb, 524288 / 4);
  convert_f2b<<<128, 256, 0, stream>>>(Wq, Wqb, 262144 / 4);
  convert_f2b<<<128, 256, 0, stream>>>(Wk, Wkb, 262144 / 4);
  convert_f2b<<<128, 256, 0, stream>>>(Wv, Wvb, 262144 / 4);
  convert_f2b<<<128, 256, 0, stream>>>(Wo, Wob, 262144 / 4);

  // q = SCALE * lang @ Wq^T
  gemm_nt<0, 0><<<dim3(4, 8, 1), 256, 0, stream>>>(langb, 0, Wqb, 0, q_ws, 0, 512, 512, 0.125f);

  for (int gi = 0; gi < g; gi++) {
    const int b0 = gi * Bg;
    transpose_f2b<<<dim3(64, 8, Bg), 256, 0, stream>>>(vis + (long)b0 * batch_elems, visT);
    // k[b'][s][i] = (Wk @ vis)^T : transposed store, ldc = 512
    gemm_nt<1, 0><<<dim3(32, 4, Bg), 256, 0, stream>>>(Wkb, 0, visT, batch_elems, k_ws, batch_elems, 512, 512, 1.0f);
    // v[b'][i][s] = Wv @ vis : natural store, ldc = 4096
    gemm_nt<0, 0><<<dim3(32, 4, Bg), 256, 0, stream>>>(Wvb, 0, visT, batch_elems, v_ws, batch_elems, 512, 4096, 1.0f);
    attn<<<dim3(8, Bg, 1), 256, 0, stream>>>(q_ws, k_ws, v_ws, tmp_ws, b0);
  }

  // out = tmp @ Wo^T, fp32 epilogue
  gemm_nt<0, 1><<<dim3(4, 8, 1), 256, 0, stream>>>(tmp_ws, 0, Wob, 0, out, 0, 512, 512, 1.0f);
}

// Round 4
// 403.661 us; speedup vs baseline: 1.1344x; 1.1344x over previous
//
#include <hip/hip_runtime.h>
#include <stdint.h>

// ---------------- common helpers ----------------
typedef __attribute__((ext_vector_type(8))) short short8;
typedef __attribute__((ext_vector_type(4))) short short4v;
typedef __attribute__((ext_vector_type(4))) float float4v;
typedef __attribute__((ext_vector_type(8))) __bf16 bf16x8;

#define NCH 8  // attention S-dim split factor

__device__ __forceinline__ float4v mfma16x16x32(short8 a, short8 b, float4v c) {
  return __builtin_amdgcn_mfma_f32_16x16x32_bf16(
      __builtin_bit_cast(bf16x8, a), __builtin_bit_cast(bf16x8, b), c, 0, 0, 0);
}

// float -> bf16 (RNE), as raw short
__device__ __forceinline__ short f2bf(float f) {
  uint32_t u = __builtin_bit_cast(uint32_t, f);
  u += 0x7fffu + ((u >> 16) & 1u);
  return (short)(u >> 16);
}

__device__ __forceinline__ float bf2f(short s) {
  return __builtin_bit_cast(float, ((uint32_t)(uint16_t)s) << 16);
}

// async 16B global->LDS via proper addrspacecast (NOT uintptr truncation).
// LDS dst must be wave-uniform base + lane*16 — all call sites comply.
__device__ __forceinline__ void load_lds16(const short* g, short* l) {
  __builtin_amdgcn_global_load_lds(
      (const __attribute__((address_space(1))) void*)g,
      (__attribute__((address_space(3))) void*)l, 16, 0, 0);
}

// ---------------- fused fp32 -> bf16 for lang + 4 weights ----------------
// grid = (128, 5); blockIdx.y selects the tensor.
__global__ __launch_bounds__(256) void convert5(
    const float* __restrict__ sl, short* __restrict__ dl,
    const float* __restrict__ s1, short* __restrict__ d1,
    const float* __restrict__ s2, short* __restrict__ d2,
    const float* __restrict__ s3, short* __restrict__ d3,
    const float* __restrict__ s4, short* __restrict__ d4) {
  const float* src; short* dst; int n4;
  switch (blockIdx.y) {
    case 0: src = sl; dst = dl; n4 = 131072; break;  // 512K elems
    case 1: src = s1; dst = d1; n4 = 65536; break;   // 256K elems
    case 2: src = s2; dst = d2; n4 = 65536; break;
    case 3: src = s3; dst = d3; n4 = 65536; break;
    default: src = s4; dst = d4; n4 = 65536; break;
  }
  const int stride = gridDim.x * blockDim.x;
  for (int i = blockIdx.x * blockDim.x + threadIdx.x; i < n4; i += stride) {
    float4v v = *(const float4v*)(src + (long)i * 4);
    short4v o;
#pragma unroll
    for (int r = 0; r < 4; r++) o[r] = f2bf(v[r]);
    *(short4v*)(dst + (long)i * 4) = o;
  }
}

// ---------------- NT GEMM: C[m,n] = scale * sum_k A[m,k]*B[n,k] ----------------
// A:[M][K] bf16 K-contig, B:[N][K] bf16 K-contig. 128x128 tile, BK=32,
// 4 waves in 2x2, each wave 64x64 (4x4 MFMA tiles). grid=(N/128, M/128, batch).
// Staging: async global_load_lds width=16 (m97 structure).
// TRANS_STORE=1: C bf16 at [n*ldc+m]; OUT_F32=1: C fp32 at [m*ldc+n];
// else bf16 at [m*ldc+n].
template <int TRANS_STORE, int OUT_F32>
__global__ __launch_bounds__(256) void gemm_nt(
    const short* __restrict__ A, long sA,
    const short* __restrict__ B, long sB,
    void* __restrict__ C, long sC,
    int K, int ldc, float scale) {
  __shared__ alignas(16) short lA[128 * 32];
  __shared__ alignas(16) short lB[128 * 32];
  const int tid = threadIdx.x;
  const int lane = tid & 63, w = tid >> 6;
  const int quad = lane >> 4, l16 = lane & 15;
  const int wm = w >> 1, wn = w & 1;
  const long m0 = (long)blockIdx.y * 128, n0 = (long)blockIdx.x * 128;
  A += blockIdx.z * sA;
  B += blockIdx.z * sB;

  float4v acc[4][4];
#pragma unroll
  for (int i = 0; i < 4; i++)
#pragma unroll
    for (int j = 0; j < 4; j++) acc[i][j] = (float4v)0.0f;

  const int srow = tid >> 2;       // 0..63
  const int scol = (tid & 3) * 8;  // element offset in BK

  for (int kt = 0; kt < K; kt += 32) {
    load_lds16(&A[(m0 + srow) * K + kt + scol], &lA[tid * 8]);
    load_lds16(&A[(m0 + 64 + srow) * K + kt + scol], &lA[2048 + tid * 8]);
    load_lds16(&B[(n0 + srow) * K + kt + scol], &lB[tid * 8]);
    load_lds16(&B[(n0 + 64 + srow) * K + kt + scol], &lB[2048 + tid * 8]);
    __syncthreads();  // compiler drains vmcnt before barrier

    short8 af[4], bf[4];
#pragma unroll
    for (int t = 0; t < 4; t++) {
      af[t] = *(const short8*)&lA[(wm * 64 + t * 16 + l16) * 32 + quad * 8];
      bf[t] = *(const short8*)&lB[(wn * 64 + t * 16 + l16) * 32 + quad * 8];
    }
#pragma unroll
    for (int i = 0; i < 4; i++)
#pragma unroll
      for (int j = 0; j < 4; j++)
        acc[i][j] = mfma16x16x32(af[i], bf[j], acc[i][j]);
    __syncthreads();
  }

  // C/D layout: col = lane&15 (n), row = quad*4 + reg (m)
  const int cm = wm * 64 + quad * 4;
  const int cn = wn * 64 + l16;
  if (OUT_F32) {
    float* Cf = (float*)C + blockIdx.z * sC;
#pragma unroll
    for (int i = 0; i < 4; i++)
#pragma unroll
      for (int j = 0; j < 4; j++) {
        const long gn = n0 + cn + j * 16;
#pragma unroll
        for (int r = 0; r < 4; r++)
          Cf[(m0 + cm + i * 16 + r) * (long)ldc + gn] = acc[i][j][r] * scale;
      }
  } else if (TRANS_STORE) {
    short* Cs = (short*)C + blockIdx.z * sC;
#pragma unroll
    for (int i = 0; i < 4; i++)
#pragma unroll
      for (int j = 0; j < 4; j++) {
        const long gm = m0 + cm + i * 16;
        const long gn = n0 + cn + j * 16;
        short4v pk;
#pragma unroll
        for (int r = 0; r < 4; r++) pk[r] = f2bf(acc[i][j][r] * scale);
        *(short4v*)&Cs[gn * (long)ldc + gm] = pk;  // gm multiple of 4 -> 8B aligned
      }
  } else {
    short* Cs = (short*)C + blockIdx.z * sC;
#pragma unroll
    for (int i = 0; i < 4; i++)
#pragma unroll
      for (int j = 0; j < 4; j++) {
        const long gn = n0 + cn + j * 16;
#pragma unroll
        for (int r = 0; r < 4; r++)
          Cs[(m0 + cm + i * 16 + r) * (long)ldc + gn] = f2bf(acc[i][j][r] * scale);
      }
  }
}

// ---------------- vis fp32 (b,c,s) -> visT bf16 (b,s,c) ----------------
// grid=(S/64, C/64, Bg), 256 thr, 64x64 LDS tile.
__global__ __launch_bounds__(256) void transpose_f2b(
    const float* __restrict__ vis, short* __restrict__ visT) {
  __shared__ alignas(16) short buf[64][68];  // 68 breaks conflicts, keeps 8B align
  const int tid = threadIdx.x;
  const long bz = blockIdx.z;
  const long s0 = (long)blockIdx.x * 64;
  const long c0 = (long)blockIdx.y * 64;
  const float* src = vis + bz * 512 * 4096;
  short* dst = visT + bz * 4096 * 512;
  const int tr = tid >> 4;         // 0..15
  const int tc4 = (tid & 15) * 4;  // 0..60
#pragma unroll
  for (int i = 0; i < 4; i++) {
    const int c = tr + i * 16;
    float4v val = *(const float4v*)&src[(c0 + c) * 4096 + s0 + tc4];
    buf[tc4 + 0][c] = f2bf(val[0]);
    buf[tc4 + 1][c] = f2bf(val[1]);
    buf[tc4 + 2][c] = f2bf(val[2]);
    buf[tc4 + 3][c] = f2bf(val[3]);
  }
  __syncthreads();
#pragma unroll
  for (int i = 0; i < 4; i++) {
    const int s = tr + i * 16;
    short4v val = *(const short4v*)&buf[s][tc4];
    *(short4v*)&dst[(s0 + s) * 512 + c0 + tc4] = val;
  }
}

// ---------------- attention partial: block = (head, batch, s-chunk) ----------------
// q:[16][64][512] bf16 (scaled), k:[Bg][4096][512] (s,i), v:[Bg][512][4096] (i,s).
// Each block handles S-range [ch*512, ch*512+512); no-max softmax partials:
// Opart[bh][ch][t][d] (fp32), lpart[bh][ch][t]. Logits clamped as NaN insurance.
__global__ __launch_bounds__(256) void attn_part(
    const short* __restrict__ q, const short* __restrict__ kws,
    const short* __restrict__ vws, float* __restrict__ Opart,
    float* __restrict__ lpart, int b0) {
  const int h = blockIdx.x;   // 8
  const int bz = blockIdx.y;  // Bg
  const int ch = blockIdx.z;  // NCH
  const int tid = threadIdx.x;
  const int lane = tid & 63, w = tid >> 6;
  const int quad = lane >> 4, l16 = lane & 15;

  __shared__ alignas(16) short lq[64 * 64];   // q tile  (t,d)
  __shared__ alignas(16) short lk[128 * 64];  // k chunk (s,d)
  __shared__ alignas(16) short lv[64 * 128];  // v chunk (d,s)
  __shared__ alignas(16) short lp[64 * 128];  // p chunk (t,s) C-layout -> A-layout
  __shared__ float lsum[64];

  const short* qb = q + ((long)(b0 + bz) * 64) * 512 + h * 64;
  const short* kb = kws + (long)bz * 4096 * 512 + h * 64;
  const short* vb = vws + (long)bz * 512 * 4096 + (long)h * 64 * 4096;

  if (tid < 64) lsum[tid] = 0.0f;
  load_lds16(&qb[(tid >> 3) * 512 + (tid & 7) * 8], &lq[tid * 8]);
  load_lds16(&qb[(32 + (tid >> 3)) * 512 + (tid & 7) * 8], &lq[2048 + tid * 8]);
  __syncthreads();

  short8 aq[4][2];  // A-frags of q, resident all kernel
#pragma unroll
  for (int mt = 0; mt < 4; mt++)
#pragma unroll
    for (int ks = 0; ks < 2; ks++)
      aq[mt][ks] = *(const short8*)&lq[(mt * 16 + l16) * 64 + ks * 32 + quad * 8];

  float4v osc[4];  // O accum: wave w owns d-tile w, all 4 t-tiles
#pragma unroll
  for (int mt = 0; mt < 4; mt++) osc[mt] = (float4v)0.0f;
  float lrow[4][4] = {};  // row-sum partials [mt][reg]

  const int send = ch * 512 + 512;
  for (int s0 = ch * 512; s0 < send; s0 += 128) {
#pragma unroll
    for (int it = 0; it < 4; it++) {
      const int li = tid + it * 256;
      load_lds16(&kb[(long)(s0 + (li >> 3)) * 512 + (li & 7) * 8], &lk[li * 8]);
    }
#pragma unroll
    for (int it = 0; it < 4; it++) {
      const int li = tid + it * 256;
      load_lds16(&vb[(long)(li >> 4) * 4096 + s0 + (li & 15) * 8], &lv[li * 8]);
    }
    __syncthreads();

    // scores: wave w covers s-tiles {2w, 2w+1}
    float4v sc[4][2];
#pragma unroll
    for (int mt = 0; mt < 4; mt++)
#pragma unroll
      for (int jn = 0; jn < 2; jn++) sc[mt][jn] = (float4v)0.0f;
#pragma unroll
    for (int ks = 0; ks < 2; ks++) {
      short8 bk[2];
#pragma unroll
      for (int jn = 0; jn < 2; jn++)
        bk[jn] = *(const short8*)&lk[((2 * w + jn) * 16 + l16) * 64 + ks * 32 + quad * 8];
#pragma unroll
      for (int mt = 0; mt < 4; mt++)
#pragma unroll
        for (int jn = 0; jn < 2; jn++)
          sc[mt][jn] = mfma16x16x32(aq[mt][ks], bk[jn], sc[mt][jn]);
    }

    // p = exp(clamped score); accumulate bf16-quantized row sums; park p in
    // LDS transposed from C-layout to A-operand layout.
#pragma unroll
    for (int mt = 0; mt < 4; mt++)
#pragma unroll
      for (int jn = 0; jn < 2; jn++)
#pragma unroll
        for (int r = 0; r < 4; r++) {
          const float scv = fminf(fmaxf(sc[mt][jn][r], -80.0f), 30.0f);
          const short sp = f2bf(__expf(scv));
          lrow[mt][r] += bf2f(sp);
          lp[(mt * 16 + quad * 4 + r) * 128 + (2 * w + jn) * 16 + l16] = sp;
        }
    __syncthreads();

    // PV: O[t, d(tile w)] += P · V
#pragma unroll
    for (int ks = 0; ks < 4; ks++) {
      const short8 bv = *(const short8*)&lv[(w * 16 + l16) * 128 + ks * 32 + quad * 8];
#pragma unroll
      for (int mt = 0; mt < 4; mt++) {
        const short8 ap = *(const short8*)&lp[(mt * 16 + l16) * 128 + ks * 32 + quad * 8];
        osc[mt] = mfma16x16x32(ap, bv, osc[mt]);
      }
    }
    __syncthreads();  // protect lk/lv/lp before next chunk's staging
  }

  // reduce row sums: 16 lanes (l16) of each quad-row hold disjoint s-columns
#pragma unroll
  for (int mt = 0; mt < 4; mt++)
#pragma unroll
    for (int r = 0; r < 4; r++) {
      float v = lrow[mt][r];
      v += __shfl_xor(v, 1);
      v += __shfl_xor(v, 2);
      v += __shfl_xor(v, 4);
      v += __shfl_xor(v, 8);
      if (l16 == 0) atomicAdd(&lsum[mt * 16 + quad * 4 + r], v);
    }
  __syncthreads();

  const long bh = bz * 8 + h;
  float* op = Opart + ((bh * NCH + ch) * 64) * 64 + w * 16 + l16;
#pragma unroll
  for (int mt = 0; mt < 4; mt++)
#pragma unroll
    for (int r = 0; r < 4; r++)
      op[(long)(mt * 16 + quad * 4 + r) * 64] = osc[mt][r];
  if (tid < 64) lpart[(bh * NCH + ch) * 64 + tid] = lsum[tid];
}

// ---------------- combine attention partials -> tmp bf16 (b,t,i) ----------------
__global__ __launch_bounds__(256) void attn_combine(
    const float* __restrict__ Opart, const float* __restrict__ lpart,
    short* __restrict__ tmp, int b0, int nbh) {
  const int total = nbh * 4096;
  for (int idx = blockIdx.x * 256 + threadIdx.x; idx < total;
       idx += gridDim.x * 256) {
    const int bh = idx >> 12;
    const int td = idx & 4095;
    const int t = td >> 6, d = td & 63;
    float o = 0.0f, l = 0.0f;
#pragma unroll
    for (int c = 0; c < NCH; c++) {
      o += Opart[((long)bh * NCH + c) * 4096 + td];
      l += lpart[(bh * NCH + c) * 64 + t];
    }
    const int b = b0 + (bh >> 3), h = bh & 7;
    tmp[((long)b * 64 + t) * 512 + h * 64 + d] = f2bf(o / l);
  }
}

// ---------------- launch ----------------
extern "C" void kernel_launch(void* const* d_in, const int* in_sizes, int n_in,
                              void* d_out, int out_size, void* d_ws, size_t ws_size,
                              hipStream_t stream) {
  (void)in_sizes; (void)n_in; (void)out_size;
  const float* vis = (const float*)d_in[0];   // [16][512][4096] fp32
  const float* lang = (const float*)d_in[1];  // [16][64][512]  fp32
  // d_in[2] = mask (int32), unused by the reference forward
  const float* Wq = (const float*)d_in[3];    // [512][512] fp32
  const float* Wk = (const float*)d_in[4];
  const float* Wv = (const float*)d_in[5];
  const float* Wo = (const float*)d_in[6];
  float* out = (float*)d_out;                 // [16][64][512] fp32

  char* ws = (char*)d_ws;
  const size_t MB = 1 << 20;
  short* q_ws = (short*)(ws + 0 * MB);    // 1 MB: scaled q bf16, (b,t,i)
  short* tmp_ws = (short*)(ws + 1 * MB);  // 1 MB: attn out bf16, (b,t,i)
  short* langb = (short*)(ws + 2 * MB);   // 1 MB
  short* Wqb = (short*)(ws + 3 * MB);     // 0.5 MB each
  short* Wkb = (short*)(ws + 3 * MB + 512 * 1024);
  short* Wvb = (short*)(ws + 4 * MB);
  short* Wob = (short*)(ws + 4 * MB + 512 * 1024);
  char* grp = ws + 5 * MB;

  const long batch_elems = 4096l * 512;  // 4 MB bf16 per batch per tensor
  // pick batch-group count so visT+k+v fit the workspace
  int g = 16;
  const int cands[5] = {1, 2, 4, 8, 16};
  for (int ci = 0; ci < 5; ci++) {
    const size_t need = 5 * MB + 3ull * (16 / cands[ci]) * batch_elems * 2;
    if (need <= ws_size) { g = cands[ci]; break; }
  }
  const int Bg = 16 / g;
  short* visT = (short*)grp;                    // [Bg][4096][512]
  short* k_ws = visT + (long)Bg * batch_elems;  // [Bg][4096][512] (s,i)
  short* v_ws = k_ws + (long)Bg * batch_elems;  // [Bg][512][4096] (i,s)
  // attn partials alias visT (dead by attn time): Bg*1MB + Bg*16KB <= Bg*4MB
  float* Opart = (float*)visT;
  float* lptr = Opart + (long)Bg * 262144;

  // fp32 -> bf16 conversions, fused into one launch
  convert5<<<dim3(128, 5), 256, 0, stream>>>(lang, langb, Wq, Wqb, Wk, Wkb,
                                             Wv, Wvb, Wo, Wob);

  // q = SCALE * lang @ Wq^T
  gemm_nt<0, 0><<<dim3(4, 8, 1), 256, 0, stream>>>(langb, 0, Wqb, 0, q_ws, 0, 512, 512, 0.125f);

  for (int gi = 0; gi < g; gi++) {
    const int b0 = gi * Bg;
    transpose_f2b<<<dim3(64, 8, Bg), 256, 0, stream>>>(vis + (long)b0 * batch_elems, visT);
    // k[b'][s][i] = (Wk @ vis)^T : transposed store, ldc = 512
    gemm_nt<1, 0><<<dim3(32, 4, Bg), 256, 0, stream>>>(Wkb, 0, visT, batch_elems, k_ws, batch_elems, 512, 512, 1.0f);
    // v[b'][i][s] = Wv @ vis : natural store, ldc = 4096
    gemm_nt<0, 0><<<dim3(32, 4, Bg), 256, 0, stream>>>(Wvb, 0, visT, batch_elems, v_ws, batch_elems, 512, 4096, 1.0f);
    attn_part<<<dim3(8, Bg, NCH), 256, 0, stream>>>(q_ws, k_ws, v_ws, Opart, lptr, b0);
    attn_combine<<<512, 256, 0, stream>>>(Opart, lptr, tmp_ws, b0, Bg * 8);
  }

  // out = tmp @ Wo^T, fp32 epilogue
  gemm_nt<0, 1><<<dim3(4, 8, 1), 256, 0, stream>>>(tmp_ws, 0, Wob, 0, out, 0, 512, 512, 1.0f);
}